// Round 8
// baseline (162.255 us; speedup 1.0000x reference)
//
#include <hip/hip_runtime.h>

// SSIM loss via separable 11-tap Gaussian — R18: ONE WAVE PER 16x16 TILE,
// zero mid-kernel barriers, zero LDS data staging.
// Why: R15/R16/R17 (6blk/256t, 8-wave occ-63%, lds-barriers+2-tile
// prefetch) all pinned at ~51us with NO pipe >40% busy. The invariant was
// the cooperative block: waves phase-locked around shared sx/sy->hq LDS,
// ~120cyc LDS round trips on the critical path, loads in short convoy
// bursts (~55 lines in flight/CU, Little's-law-starved at 1 TB/s). Fix =
// remove cooperation, not tune it.
// Structure (per wave, tile = 16x16 out at (16ty,16tx), window 32x32 at
// (16ty-8,16tx-8)):
//  - Load window DIRECTLY to registers: lane(lg=lane>>4,lm=lane&15) reads
//    rows 16b+lm, cols 8lg..8lg+7 (2 aligned float4) x 2 bands x {x,y}.
//    This IS the mfma_16x16x32 A-operand layout (row=lm, k=8lg+e).
//  - Horizontal: per quantity q in {x,y,xx,yy,xy}: d_b = mfma32(data_b, bt)
//    with taps bt[e] = g[8lg+e-lm-3] (out col n needs window cols n+3..n+13).
//  - KEY: B-phase D-layout (col=lm, row=4lg+reg) == B-operand fragment of
//    mfma_f32_16x16x16f16 (col=lm, k=4lg+e). So vertical conv = two chained
//    K=16 MFMAs consuming packed-f16 D regs IN PLACE: no h matrix, no LDS,
//    no shuffles. C taps: band b frag ca_b[e] = g[16b+4lg+e-lm-3].
//  - Taps from 64-entry LDS pair-table tbp[i]=(tap(i-19),tap(i-18)), f16
//    center-corrected; any window of consecutive pairs is 2 u32 reads.
//  - Block = 4 independent waves; barriers ONLY at start (gsf/tbp build)
//    and end (4-float wred). 12288 blocks, XCD-bijective swizzle.
// Reduction history (do NOT re-fuse): R13 fences -> 9x regression; R14
// relaxed same-line atomics -> 3x (XCD ping-pong). Two-kernel scheme stands.
// Numerics unchanged: f16 data/taps (center-corrected), f32 accum, h packed
// to f16 between passes -> same absmax class (0.0039, passes).

typedef __fp16 f16x8 __attribute__((ext_vector_type(8)));
typedef __fp16 f16x4 __attribute__((ext_vector_type(4)));
typedef float  f32x4 __attribute__((ext_vector_type(4)));
typedef unsigned u32x2 __attribute__((ext_vector_type(2)));
typedef unsigned u32x4 __attribute__((ext_vector_type(4)));

__device__ __forceinline__ unsigned pk2(float a, float b) {
    return __builtin_bit_cast(unsigned, __builtin_amdgcn_cvt_pkrtz(a, b));
}
__device__ __forceinline__ f32x4 mfmaB(f16x8 a, f16x8 b, f32x4 c) {
    return __builtin_amdgcn_mfma_f32_16x16x32_f16(a, b, c, 0, 0, 0);
}
__device__ __forceinline__ f32x4 mfmaC(f16x4 a, f16x4 b, f32x4 c) {
    return __builtin_amdgcn_mfma_f32_16x16x16f16(a, b, c, 0, 0, 0);
}

__global__ __launch_bounds__(256, 6) void ssim_main(
    const float* __restrict__ xg, const float* __restrict__ yg,
    const float* __restrict__ w2d, float* __restrict__ part)
{
    __shared__ float gsf[11];
    __shared__ unsigned tbp[64];
    __shared__ float wred[4];

    const int tid = threadIdx.x;

    // 1D kernel = row sums of the 2D window (outer(g,g), sum 1).
    if (tid < 11) {
        float s = 0.0f;
        #pragma unroll
        for (int j = 0; j < 11; ++j) s += w2d[tid * 11 + j];
        gsf[tid] = s;
    }
    __syncthreads();

    // Pair-table: tbp[i] = (tap(i-19), tap(i-18)) packed f16x2; taps f16-
    // rounded with center correction so the f16 tap sum ~= 1.
    if (tid < 64) {
        float ssum = 0.0f;
        #pragma unroll
        for (int k = 0; k < 11; ++k)
            if (k != 5) ssum += (float)(__fp16)gsf[k];
        const __fp16 cc = (__fp16)(1.0f - ssum);
        auto tap = [&](int t) -> __fp16 {
            if ((unsigned)t > 10u) return (__fp16)0.f;
            return (t == 5) ? cc : (__fp16)gsf[t];
        };
        const int t = tid - 19;
        const unsigned short lo = __builtin_bit_cast(unsigned short, tap(t));
        const unsigned short hi = __builtin_bit_cast(unsigned short, tap(t + 1));
        tbp[tid] = (unsigned)lo | ((unsigned)hi << 16);
    }
    __syncthreads();

    const int lane = tid & 63, wv = tid >> 6;
    const int lm = lane & 15, lg = lane >> 4;

    // XCD-bijective swizzle over 12288 blocks; tile id = 4*swz + wv.
    const int nblk = (int)gridDim.x;
    const int bid = (int)blockIdx.x;
    const int swz = (bid & 7) * (nblk >> 3) + (bid >> 3);
    const int t = swz * 4 + wv;
    const int tz = t >> 10, ty = (t >> 5) & 31, tx = t & 31;
    const int x0 = 16 * tx - 8, y0 = 16 * ty - 8;
    const bool border = (tx == 0) | (tx == 31) | (ty == 0) | (ty == 31);
    const float* __restrict__ xp = xg + (size_t)tz * (512 * 512);
    const float* __restrict__ yp = yg + (size_t)tz * (512 * 512);

    // Window load: band b rows 16b+lm, cols x0+8lg..+7 -> f16x8 (A-operand).
    auto ldband = [&](const float* __restrict__ p, int b) -> f16x8 {
        const int gr = y0 + 16 * b + lm;
        const int gc0 = x0 + 8 * lg;
        u32x4 w;
        if (!border) {                        // wave-uniform branch
            const float4 v0 = *(const float4*)&p[gr * 512 + gc0];
            const float4 v1 = *(const float4*)&p[gr * 512 + gc0 + 4];
            w = (u32x4){pk2(v0.x, v0.y), pk2(v0.z, v0.w),
                        pk2(v1.x, v1.y), pk2(v1.z, v1.w)};
        } else {
            const bool rok = (unsigned)gr < 512u;
            float v[8];
            #pragma unroll
            for (int j = 0; j < 8; ++j) {
                const int gc = gc0 + j;
                const bool ok = rok & ((unsigned)gc < 512u);
                const int o = ok ? (gr * 512 + gc) : 0;
                v[j] = ok ? p[o] : 0.f;
            }
            w = (u32x4){pk2(v[0], v[1]), pk2(v[2], v[3]),
                        pk2(v[4], v[5]), pk2(v[6], v[7])};
        }
        return __builtin_bit_cast(f16x8, w);
    };

    const f16x8 xd0 = ldband(xp, 0), xd1 = ldband(xp, 1);
    const f16x8 yd0 = ldband(yp, 0), yd1 = ldband(yp, 1);

    // Tap fragments from the pair-table.
    //  B (K=32): bt[e] = g[8lg+e-lm-3]   -> pairs at ib=8lg-lm+16, +2,+4,+6
    //  C (K=16) band b: ca_b[e] = g[16b+4lg+e-lm-3] -> pairs at
    //    ic=4lg-lm+16 (+16 for band 1), +2.   All indices in [1,46].
    f16x8 bt;
    f16x4 ca0, ca1;
    {
        const int ib = 8 * lg - lm + 16;
        const u32x4 wb = {tbp[ib], tbp[ib + 2], tbp[ib + 4], tbp[ib + 6]};
        bt = __builtin_bit_cast(f16x8, wb);
        const int ic = 4 * lg - lm + 16;
        const u32x2 w0 = {tbp[ic], tbp[ic + 2]};
        const u32x2 w1 = {tbp[ic + 16], tbp[ic + 18]};
        ca0 = __builtin_bit_cast(f16x4, w0);
        ca1 = __builtin_bit_cast(f16x4, w1);
    }

    const f32x4 z4 = {0.f, 0.f, 0.f, 0.f};
    f32x4 acc[5];
    #pragma unroll
    for (int q = 0; q < 5; ++q) {
        f16x8 a0, a1;
        if (q == 0)      { a0 = xd0;       a1 = xd1; }
        else if (q == 1) { a0 = yd0;       a1 = yd1; }
        else if (q == 2) { a0 = xd0 * xd0; a1 = xd1 * xd1; }
        else if (q == 3) { a0 = yd0 * yd0; a1 = yd1 * yd1; }
        else             { a0 = xd0 * yd0; a1 = xd1 * yd1; }
        // Horizontal: h rows (window rows) x out cols, per band.
        const f32x4 d0 = mfmaB(a0, bt, z4);
        const f32x4 d1 = mfmaB(a1, bt, z4);
        // Pack D rows (4lg+{0,1},{2,3}) -> EXACTLY the K=16 B-op fragment.
        const u32x2 h0 = {pk2(d0[0], d0[1]), pk2(d0[2], d0[3])};
        const u32x2 h1 = {pk2(d1[0], d1[1]), pk2(d1[2], d1[3])};
        // Vertical: two chained K=16 MFMAs (k=0..15 then 16..31).
        const f32x4 p0 = mfmaC(ca0, __builtin_bit_cast(f16x4, h0), z4);
        acc[q]         = mfmaC(ca1, __builtin_bit_cast(f16x4, h1), p0);
    }

    // SSIM epilogue: lane holds out col 16tx+lm, rows 16ty+4lg+{0..3}.
    float lsum = 0.0f;
    const float C1 = 1e-4f, C2 = 9e-4f;
    #pragma unroll
    for (int r = 0; r < 4; ++r) {
        const float mx = acc[0][r], my = acc[1][r];
        const float exx = acc[2][r], eyy = acc[3][r];
        const float exy = acc[4][r];
        const float mx2 = mx * mx, my2 = my * my, mxy = mx * my;
        const float vx = exx - mx2, vy = eyy - my2, vxy = exy - mxy;
        const float num = (2.0f * mxy + C1) * (2.0f * vxy + C2);
        const float den = (mx2 + my2 + C1) * (vx + vy + C2) + 1e-12f;
        lsum = fmaf(num, __builtin_amdgcn_rcpf(den), lsum);
    }

    // Wave reduce -> 4-float LDS -> one plain store per block.
    #pragma unroll
    for (int off = 32; off > 0; off >>= 1)
        lsum += __shfl_down(lsum, off, 64);
    if ((tid & 63) == 0) wred[tid >> 6] = lsum;
    __syncthreads();
    if (tid == 0)
        part[bid] = wred[0] + wred[1] + wred[2] + wred[3];
}

__global__ __launch_bounds__(1024) void ssim_reduce(
    const float* __restrict__ part, float* __restrict__ out,
    int n, float invN)
{
    __shared__ float wred[16];
    float s = 0.0f;
    for (int i = threadIdx.x; i < n; i += 1024) s += part[i];
    #pragma unroll
    for (int off = 32; off > 0; off >>= 1)
        s += __shfl_down(s, off, 64);
    if ((threadIdx.x & 63) == 0) wred[threadIdx.x >> 6] = s;
    __syncthreads();
    if (threadIdx.x == 0) {
        float tot = 0.0f;
        #pragma unroll
        for (int w = 0; w < 16; ++w) tot += wred[w];
        out[0] = 1.0f - tot * invN;
    }
}

extern "C" void kernel_launch(void* const* d_in, const int* in_sizes, int n_in,
                              void* d_out, int out_size, void* d_ws, size_t ws_size,
                              hipStream_t stream) {
    const float* x   = (const float*)d_in[0];
    const float* y   = (const float*)d_in[1];
    const float* w2d = (const float*)d_in[2];  // (3,1,11,11); channels identical
    float* out  = (float*)d_out;
    float* part = (float*)d_ws;                // 12288 floats = 48 KB

    const int H = 512, W = 512;
    const int total = in_sizes[0];              // 16*3*512*512
    const int Z = total / (H * W);              // 48

    // 48 images x 32x32 tiles of 16x16 = 49152 waves = 12288 blocks x 4.
    const int nblk = Z * 1024 / 4;
    ssim_main<<<dim3(nblk), 256, 0, stream>>>(x, y, w2d, part);

    const float invN = 1.0f / (float)total;
    ssim_reduce<<<1, 1024, 0, stream>>>(part, out, nblk, invN);
}

// Round 10
// 142.310 us; speedup vs baseline: 1.1402x; 1.1402x over previous
//
#include <hip/hip_runtime.h>

// SSIM loss via separable 11-tap Gaussian — R19 (resubmit; R9's bench run
// died to a container-acquire infra failure, kernel never executed).
// Hybrid of R15's memory pattern and R18's compute pattern.
// Evidence: R15-R17 (cooperative staging + hq LDS round-trip) pinned at
// ~51us, no pipe >40%. R18 (fully independent waves, global loads per
// wave) = 71us: compute formulation VERIFIED correct + conflict-free, but
// each load instr touched 16 image rows (16 lines/instr, uncoalesced) ->
// transaction-bound. R19 takes the good halves of each:
//  - COALESCED cooperative staging (R15-style): 48x48 f32 window ->
//    float4 loads -> cvt_pk -> f16 LDS (48 rows x 28 words; SXW=28 keeps
//    every compute ds_read_b128 16B-aligned; bank overlap 2-way = free).
//  - PER-WAVE INDEPENDENT compute (R18-verified): wave wv owns 16x16 out
//    sub-tile (wr=wv>>1, wc=wv&1). Data A-operand = 4x ds_read_b128
//    (rows 16wr+16b+lm, word col 8wc+4lg). Horizontal = mfma_16x16x32
//    per band/quantity (taps bt[e]=g[8lg+e-lm-3]); B-phase D-layout
//    (col=lm,row=4lg+reg) IS the K=16 B-operand fragment (col=lm,k=4lg+e),
//    so vertical = two chained mfma_16x16x16f16 (taps ca_b[e]=
//    g[16b+4lg+e-lm-3]) consuming packed-f16 D regs in place. No hq
//    matrix, no inter-wave exchange, 5 quantities {x,y,xx,yy,xy}.
//  - ONE mid-kernel ldsBarrier (lgkmcnt-only; staging + tap table).
//    gsf+tbp built entirely inside wave 0 -> intra-wave LDS ordering,
//    no extra barrier. Global loads issued BEFORE tap build (overlap).
// Reduction history (do NOT re-fuse): R13 fences -> 9x regression; R14
// relaxed same-line atomics -> 3x (XCD ping-pong). Two-kernel scheme.
// Numerics: f16 data/taps (center-corrected), f32 accum, h repacked f16
// between passes -> absmax 0.0039 class (passed R18 with identical math).

typedef __fp16 f16x8 __attribute__((ext_vector_type(8)));
typedef __fp16 f16x4 __attribute__((ext_vector_type(4)));
typedef float  f32x4 __attribute__((ext_vector_type(4)));
typedef unsigned u32x2 __attribute__((ext_vector_type(2)));
typedef unsigned u32x4 __attribute__((ext_vector_type(4)));

__device__ __forceinline__ unsigned pk2(float a, float b) {
    return __builtin_bit_cast(unsigned, __builtin_amdgcn_cvt_pkrtz(a, b));
}
__device__ __forceinline__ f32x4 mfmaB(f16x8 a, f16x8 b, f32x4 c) {
    return __builtin_amdgcn_mfma_f32_16x16x32_f16(a, b, c, 0, 0, 0);
}
__device__ __forceinline__ f32x4 mfmaC(f16x4 a, f16x4 b, f32x4 c) {
    return __builtin_amdgcn_mfma_f32_16x16x16f16(a, b, c, 0, 0, 0);
}
// LDS-only barrier: orders LDS across waves WITHOUT draining vmcnt.
__device__ __forceinline__ void ldsBarrier() {
    asm volatile("s_waitcnt lgkmcnt(0)\n\ts_barrier" ::: "memory");
}

#define SXW 28   // staged words/row (48 f16 cols used + pad); mult of 4 ->
                 // (16wr+16b+lm)*SXW + 8wc + 4lg is 16B-aligned for b128

__global__ __launch_bounds__(256, 8) void ssim_main(
    const float* __restrict__ xg, const float* __restrict__ yg,
    const float* __restrict__ w2d, float* __restrict__ part)
{
    __shared__ __align__(16) unsigned sx[48 * SXW];   // 5376 B
    __shared__ __align__(16) unsigned sy[48 * SXW];   // 5376 B
    __shared__ unsigned tbp[64];                      // 256 B pair-table
    __shared__ float gsf[11];
    __shared__ float wred[4];

    const int tid = threadIdx.x;

    // XCD-bijective swizzle over 12288 blocks; block = 32x32 out tile.
    const int nblk = (int)gridDim.x;
    const int bid = (int)blockIdx.x;
    const int swz = (bid & 7) * (nblk >> 3) + (bid >> 3);
    const int tz = swz >> 8, ty = (swz >> 4) & 15, tx = swz & 15;
    const int X0 = 32 * tx - 8, Y0 = 32 * ty - 8;     // staged window origin
    const bool inter = (tx > 0) & (tx < 15) & (ty > 0) & (ty < 15);
    const float* __restrict__ xp = xg + (size_t)tz * (512 * 512);
    const float* __restrict__ yp = yg + (size_t)tz * (512 * 512);

    // Issue staging loads FIRST (latency overlaps tap-table build).
    // 48 rows x 12 float4 = 576 items x {x,y}; thread gets items tid,
    // tid+256, and (tid<64) tid+512.
    float4 lx0, ly0, lx1, ly1, lx2, ly2;
    const bool h2 = tid < 64;
    auto ldit = [&](int it, float4& vx, float4& vy) {
        const int r = it / 12, c4 = it - r * 12;
        const int gr = Y0 + r, gc0 = X0 + 4 * c4;
        if (inter) {                                  // block-uniform branch
            const int o = gr * 512 + gc0;
            vx = *(const float4*)&xp[o];
            vy = *(const float4*)&yp[o];
        } else {
            const bool rok = (unsigned)gr < 512u;
            float tx4[4], ty4[4];
            #pragma unroll
            for (int j = 0; j < 4; ++j) {
                const int gc = gc0 + j;
                const bool ok = rok & ((unsigned)gc < 512u);
                const int o = ok ? (gr * 512 + gc) : 0;
                tx4[j] = ok ? xp[o] : 0.f;
                ty4[j] = ok ? yp[o] : 0.f;
            }
            vx = make_float4(tx4[0], tx4[1], tx4[2], tx4[3]);
            vy = make_float4(ty4[0], ty4[1], ty4[2], ty4[3]);
        }
    };
    ldit(tid, lx0, ly0);
    ldit(tid + 256, lx1, ly1);
    if (h2) ldit(tid + 512, lx2, ly2);

    // Tap table, built ENTIRELY by wave 0 (intra-wave LDS ordering -> no
    // barrier between gsf write and tbp build). 1D kernel = row sums of
    // outer(g,g); taps f16-rounded with center correction (sum ~= 1);
    // tbp[i] = (tap(i-19), tap(i-18)) packed f16x2.
    if (tid < 11) {
        float s = 0.0f;
        #pragma unroll
        for (int j = 0; j < 11; ++j) s += w2d[tid * 11 + j];
        gsf[tid] = s;
    }
    if (tid < 64) {
        float ssum = 0.0f;
        #pragma unroll
        for (int k = 0; k < 11; ++k)
            if (k != 5) ssum += (float)(__fp16)gsf[k];
        const __fp16 cc = (__fp16)(1.0f - ssum);
        auto tap = [&](int t) -> __fp16 {
            if ((unsigned)t > 10u) return (__fp16)0.f;
            return (t == 5) ? cc : (__fp16)gsf[t];
        };
        const int t = tid - 19;
        const unsigned short lo = __builtin_bit_cast(unsigned short, tap(t));
        const unsigned short hi = __builtin_bit_cast(unsigned short, tap(t + 1));
        tbp[tid] = (unsigned)lo | ((unsigned)hi << 16);
    }

    // Stage to LDS (vmcnt waits fold in here), then ONE barrier.
    auto wrt = [&](int it, const float4& vx, const float4& vy) {
        const int r = it / 12, c4 = it - r * 12;
        *(uint2*)&sx[r * SXW + 2 * c4] =
            make_uint2(pk2(vx.x, vx.y), pk2(vx.z, vx.w));
        *(uint2*)&sy[r * SXW + 2 * c4] =
            make_uint2(pk2(vy.x, vy.y), pk2(vy.z, vy.w));
    };
    wrt(tid, lx0, ly0);
    wrt(tid + 256, lx1, ly1);
    if (h2) wrt(tid + 512, lx2, ly2);
    ldsBarrier();                        // [1] sx/sy + tbp visible

    const int lane = tid & 63, wv = tid >> 6;
    const int lm = lane & 15, lg = lane >> 4;
    const int wr = wv >> 1, wc = wv & 1;

    // Tap fragments (verified R18): B bt[e]=g[8lg+e-lm-3]; C band b
    // ca_b[e]=g[16b+4lg+e-lm-3]. Pair indices all in [1,46].
    f16x8 bt;
    f16x4 ca0, ca1;
    {
        const int ib = 8 * lg - lm + 16;
        const u32x4 wb = {tbp[ib], tbp[ib + 2], tbp[ib + 4], tbp[ib + 6]};
        bt = __builtin_bit_cast(f16x8, wb);
        const int ic = 4 * lg - lm + 16;
        const u32x2 w0 = {tbp[ic], tbp[ic + 2]};
        const u32x2 w1 = {tbp[ic + 16], tbp[ic + 18]};
        ca0 = __builtin_bit_cast(f16x4, w0);
        ca1 = __builtin_bit_cast(f16x4, w1);
    }

    // Data A-operands: band b = window rows 16wr+16b+lm, word col 8wc+4lg.
    // 4 x ds_read_b128, 16B-aligned, 2-way bank overlap max (free).
    const int rbase = (16 * wr + lm) * SXW + 8 * wc + 4 * lg;
    const f16x8 xd0 = __builtin_bit_cast(f16x8, *(const u32x4*)&sx[rbase]);
    const f16x8 xd1 = __builtin_bit_cast(f16x8, *(const u32x4*)&sx[rbase + 16 * SXW]);
    const f16x8 yd0 = __builtin_bit_cast(f16x8, *(const u32x4*)&sy[rbase]);
    const f16x8 yd1 = __builtin_bit_cast(f16x8, *(const u32x4*)&sy[rbase + 16 * SXW]);

    const f32x4 z4 = {0.f, 0.f, 0.f, 0.f};
    f32x4 acc[5];
    #pragma unroll
    for (int q = 0; q < 5; ++q) {
        f16x8 a0, a1;
        if (q == 0)      { a0 = xd0;       a1 = xd1; }
        else if (q == 1) { a0 = yd0;       a1 = yd1; }
        else if (q == 2) { a0 = xd0 * xd0; a1 = xd1 * xd1; }
        else if (q == 3) { a0 = yd0 * yd0; a1 = yd1 * yd1; }
        else             { a0 = xd0 * yd0; a1 = xd1 * yd1; }
        // Horizontal conv per band.
        const f32x4 d0 = mfmaB(a0, bt, z4);
        const f32x4 d1 = mfmaB(a1, bt, z4);
        // Pack D rows (4lg+{0,1},{2,3}) -> EXACTLY the K=16 B-op fragment.
        const u32x2 h0 = {pk2(d0[0], d0[1]), pk2(d0[2], d0[3])};
        const u32x2 h1 = {pk2(d1[0], d1[1]), pk2(d1[2], d1[3])};
        // Vertical conv: two chained K=16 MFMAs (k=0..15, 16..31).
        const f32x4 p0 = mfmaC(ca0, __builtin_bit_cast(f16x4, h0), z4);
        acc[q]         = mfmaC(ca1, __builtin_bit_cast(f16x4, h1), p0);
    }

    // SSIM epilogue: lane holds out col 32tx+16wc+lm, rows 32ty+16wr+4lg+r.
    float lsum = 0.0f;
    const float C1 = 1e-4f, C2 = 9e-4f;
    #pragma unroll
    for (int r = 0; r < 4; ++r) {
        const float mx = acc[0][r], my = acc[1][r];
        const float exx = acc[2][r], eyy = acc[3][r];
        const float exy = acc[4][r];
        const float mx2 = mx * mx, my2 = my * my, mxy = mx * my;
        const float vx = exx - mx2, vy = eyy - my2, vxy = exy - mxy;
        const float num = (2.0f * mxy + C1) * (2.0f * vxy + C2);
        const float den = (mx2 + my2 + C1) * (vx + vy + C2) + 1e-12f;
        lsum = fmaf(num, __builtin_amdgcn_rcpf(den), lsum);
    }

    // Wave reduce -> 4-float LDS -> one plain store per block.
    #pragma unroll
    for (int off = 32; off > 0; off >>= 1)
        lsum += __shfl_down(lsum, off, 64);
    if ((tid & 63) == 0) wred[tid >> 6] = lsum;
    ldsBarrier();                        // [2]
    if (tid == 0)
        part[bid] = wred[0] + wred[1] + wred[2] + wred[3];
}

__global__ __launch_bounds__(1024) void ssim_reduce(
    const float* __restrict__ part, float* __restrict__ out,
    int n, float invN)
{
    __shared__ float wred[16];
    float s = 0.0f;
    for (int i = threadIdx.x; i < n; i += 1024) s += part[i];
    #pragma unroll
    for (int off = 32; off > 0; off >>= 1)
        s += __shfl_down(s, off, 64);
    if ((threadIdx.x & 63) == 0) wred[threadIdx.x >> 6] = s;
    __syncthreads();
    if (threadIdx.x == 0) {
        float tot = 0.0f;
        #pragma unroll
        for (int w = 0; w < 16; ++w) tot += wred[w];
        out[0] = 1.0f - tot * invN;
    }
}

extern "C" void kernel_launch(void* const* d_in, const int* in_sizes, int n_in,
                              void* d_out, int out_size, void* d_ws, size_t ws_size,
                              hipStream_t stream) {
    const float* x   = (const float*)d_in[0];
    const float* y   = (const float*)d_in[1];
    const float* w2d = (const float*)d_in[2];  // (3,1,11,11); channels identical
    float* out  = (float*)d_out;
    float* part = (float*)d_ws;                // 12288 floats = 48 KB

    const int H = 512, W = 512;
    const int total = in_sizes[0];              // 16*3*512*512
    const int Z = total / (H * W);              // 48

    // 48 images x 16x16 tiles of 32x32 px = 12288 blocks (4 waves each).
    const int nblk = Z * 256;
    ssim_main<<<dim3(nblk), 256, 0, stream>>>(x, y, w2d, part);

    const float invN = 1.0f / (float)total;
    ssim_reduce<<<1, 1024, 0, stream>>>(part, out, nblk, invN);
}